// Round 2
// baseline (6319.288 us; speedup 1.0000x reference)
//
#include <hip/hip_runtime.h>
#include <math.h>

#define B_ 32
#define T_ 128
#define D_ 512
#define U_ 512
#define G_ 2048   // 4U
#define NGRP 8    // batch groups (mapped 1:1 to XCDs via blockIdx%8 swizzle)
#define GB 4      // batches per group
#define WPG 32    // workgroups per group
#define NT 512    // threads per WG
#define GK 512    // K dim of precompute GEMMs

// ---------------------------------------------------------------------------
// Precompute GEMM: C[M,N] = A[M,512] @ W[512,N] + bias[N]  (unchanged, ~75us)
// ---------------------------------------------------------------------------
__global__ __launch_bounds__(256) void gemm_bias(const float* __restrict__ A,
                                                 const float* __restrict__ W,
                                                 const float* __restrict__ bias,
                                                 float* __restrict__ C, int N) {
  __shared__ float As[16][68];
  __shared__ float Ws[16][64];
  const int tid = threadIdx.x;
  const int rowbase = blockIdx.y * 64;
  const int colbase = blockIdx.x * 64;
  const int ty = tid >> 4, tx = tid & 15;
  const int ar = tid >> 2, ak = (tid & 3) << 2;
  const int wk = tid >> 4, wc = (tid & 15) << 2;
  float acc[4][4] = {{0.f, 0.f, 0.f, 0.f}};
  for (int k0 = 0; k0 < GK; k0 += 16) {
    float4 av = *(const float4*)(A + (size_t)(rowbase + ar) * GK + k0 + ak);
    float4 wv = *(const float4*)(W + (size_t)(k0 + wk) * N + colbase + wc);
    __syncthreads();
    As[ak + 0][ar] = av.x;
    As[ak + 1][ar] = av.y;
    As[ak + 2][ar] = av.z;
    As[ak + 3][ar] = av.w;
    *(float4*)(&Ws[wk][wc]) = wv;
    __syncthreads();
#pragma unroll
    for (int kk = 0; kk < 16; ++kk) {
      float4 a = *(const float4*)(&As[kk][ty << 2]);
      float4 wv2 = *(const float4*)(&Ws[kk][tx << 2]);
      float a4[4] = {a.x, a.y, a.z, a.w};
      float w4[4] = {wv2.x, wv2.y, wv2.z, wv2.w};
#pragma unroll
      for (int i = 0; i < 4; ++i)
#pragma unroll
        for (int jj = 0; jj < 4; ++jj) acc[i][jj] += a4[i] * w4[jj];
    }
  }
  float4 bv = *(const float4*)(bias + colbase + (tx << 2));
#pragma unroll
  for (int i = 0; i < 4; ++i) {
    float4 o;
    o.x = acc[i][0] + bv.x;
    o.y = acc[i][1] + bv.y;
    o.z = acc[i][2] + bv.z;
    o.w = acc[i][3] + bv.w;
    *(float4*)(C + (size_t)(rowbase + (ty << 2) + i) * N + colbase + (tx << 2)) = o;
  }
}

__global__ __launch_bounds__(256) void transpose_tu(const float* __restrict__ in,
                                                    float* __restrict__ outp) {
  __shared__ float tile[32][33];
  const int b = blockIdx.y;
  const int tt0 = (blockIdx.x & 3) * 32;
  const int uu0 = (blockIdx.x >> 2) * 32;
  const int lx = threadIdx.x & 31, ly = threadIdx.x >> 5;
#pragma unroll
  for (int qq = 0; qq < 4; ++qq) {
    int tt = tt0 + ly + qq * 8;
    tile[ly + qq * 8][lx] = in[((size_t)b * T_ + tt) * U_ + uu0 + lx];
  }
  __syncthreads();
#pragma unroll
  for (int qq = 0; qq < 4; ++qq) {
    int uu = uu0 + ly + qq * 8;
    outp[((size_t)b * U_ + uu) * T_ + tt0 + lx] = tile[lx][ly + qq * 8];
  }
}

// ---------------------------------------------------------------------------
// tanh with graceful saturation: expf(-inf)=0 -> -1 ; expf(+inf)=inf -> +1
// ---------------------------------------------------------------------------
__device__ __forceinline__ float tanh_fast(float x) {
  return 1.f - 2.f / (__expf(2.f * x) + 1.f);
}

// Per-group spin barrier (WPG workgroups, same XCD by swizzle heuristic).
// Agent scope keeps it correct even if the XCD mapping assumption is wrong.
__device__ __forceinline__ void grp_barrier(unsigned* ctr, unsigned target) {
  __syncthreads();
  if (threadIdx.x == 0) {
    __hip_atomic_fetch_add(ctr, 1u, __ATOMIC_RELEASE, __HIP_MEMORY_SCOPE_AGENT);
    while (__hip_atomic_load(ctr, __ATOMIC_ACQUIRE, __HIP_MEMORY_SCOPE_AGENT) <
           target) {
      __builtin_amdgcn_s_sleep(2);
    }
  }
  __syncthreads();
}

// ---------------------------------------------------------------------------
// Recurrence: 8 groups x 32 WGs x 512 threads. Group bg = blockIdx%8 (XCD),
// WG w owns: u-slice [w*16,w*16+16) for hU/scores/z/c/h, and the 64 gate
// columns {g*512 + w*16 + ui} (all 4 gates of its u-slice -> h update local).
// Weights read once per GROUP per step (4x less traffic than per-batch).
// 3 same-XCD barriers per step.
// ---------------------------------------------------------------------------
__global__ __launch_bounds__(NT) void attlstm_rec(
    const float* __restrict__ x,      // (B,T,D)
    const float* __restrict__ xk,     // (B,T,4U)
    const float* __restrict__ attxT,  // (B,U,T)
    const float* __restrict__ Rk,     // (U,4U)
    const float* __restrict__ Ak,     // (D,4U)
    const float* __restrict__ Um,     // (U,U)
    const float* __restrict__ V,      // (U)
    float* __restrict__ h_g,          // (B,U)
    float* __restrict__ sp_g,         // (NGRP,WPG,GB,T)
    float* __restrict__ z_g,          // (B,D)
    unsigned* __restrict__ bars,      // (NGRP,64)
    float* __restrict__ out) {        // (B,T,U)
  const int bg = blockIdx.x & 7;
  const int w = blockIdx.x >> 3;
  const int tid = threadIdx.x;
  const int u0 = w * 16;

  __shared__ float h_s[GB][U_];     // 8 KB
  __shared__ float z_s[GB][D_];     // 8 KB
  __shared__ float sc_s[GB][T_];    // 2 KB
  __shared__ float4 red_s[512];     // 8 KB reduction scratch (shared by phases)
  __shared__ float ghr_s[GB][64];   // 1 KB
  __shared__ float act_s[GB][64];   // 1 KB
  __shared__ float hU_s[GB][16];
  __shared__ float c_s[GB][16];
  __shared__ float m_s[GB], il_s[GB];
  __shared__ float Vs[16];

  // --- per-thread role mappings ---
  // matvec (ghr/gza): 16 col-quads x 4 batches x 8 K-splits
  const int kh8 = tid >> 6;          // 0..7   K-range 64
  const int bA = (tid >> 4) & 3;     // batch
  const int c4 = tid & 15;           // col-quad
  const int gA = c4 >> 2;            // gate 0..3
  const int gcol = gA * U_ + u0 + (c4 & 3) * 4;
  // hU: 4 u-quads x 4 batches x 32 K-splits
  const int khU = tid >> 4;          // 0..31  K-range 16
  const int bU = (tid >> 2) & 3;
  const int u4 = tid & 3;
  // scores / softmax / exchanges: (batch, t)
  const int bS = tid >> 7;           // 0..3
  const int tS = tid & 127;
  // z: 4 d-quads x 4 batches x 32 t-splits
  const int tkh = tid >> 4;          // 0..31  t-range 4
  const int bZ = (tid >> 2) & 3;
  const int d4 = tid & 3;

  for (int i = tid; i < GB * U_; i += NT) ((float*)h_s)[i] = 0.f;
  if (tid < GB * 16) ((float*)c_s)[tid] = 0.f;
  if (tid < 16) Vs[tid] = V[u0 + tid];
  unsigned* ctr = bars + bg * 64;
  unsigned epoch = 0;
  __syncthreads();

  for (int t = 0; t < T_; ++t) {
    // ========== P1: ghr = h@Rk (cols), hU = h@Um (u-slice), score partials ==
    {
      float ax = 0.f, ay = 0.f, az = 0.f, aw = 0.f;
      const float* Rp = Rk + (size_t)(kh8 * 64) * G_ + gcol;
      const float* hp = &h_s[bA][kh8 * 64];
#pragma unroll 8
      for (int i = 0; i < 64; ++i) {
        float4 wv = *(const float4*)(Rp + (size_t)i * G_);
        float hv = hp[i];
        ax += hv * wv.x; ay += hv * wv.y; az += hv * wv.z; aw += hv * wv.w;
      }
      red_s[(kh8 * GB + bA) * 16 + c4] = make_float4(ax, ay, az, aw);
    }
    __syncthreads();
    if (tid < 256) {
      int b = tid >> 6, c = tid & 63;
      int cq = c >> 2, comp = c & 3;
      float s = 0.f;
#pragma unroll
      for (int k = 0; k < 8; ++k)
        s += ((const float*)&red_s[(k * GB + b) * 16 + cq])[comp];
      ghr_s[b][c] = s;
    }
    __syncthreads();
    {
      float ax = 0.f, ay = 0.f, az = 0.f, aw = 0.f;
      const float* Up = Um + (size_t)(khU * 16) * U_ + u0 + u4 * 4;
      const float* hp = &h_s[bU][khU * 16];
#pragma unroll
      for (int i = 0; i < 16; ++i) {
        float4 wv = *(const float4*)(Up + (size_t)i * U_);
        float hv = hp[i];
        ax += hv * wv.x; ay += hv * wv.y; az += hv * wv.z; aw += hv * wv.w;
      }
      red_s[(khU * GB + bU) * 4 + u4] = make_float4(ax, ay, az, aw);
    }
    __syncthreads();
    if (tid < 16) {
      int b = tid >> 2, uq = tid & 3;
      float sx = 0.f, sy = 0.f, sz = 0.f, sw = 0.f;
#pragma unroll
      for (int k = 0; k < 32; ++k) {
        float4 v4 = red_s[(k * GB + b) * 4 + uq];
        sx += v4.x; sy += v4.y; sz += v4.z; sw += v4.w;
      }
      hU_s[b][uq * 4 + 0] = sx;
      hU_s[b][uq * 4 + 1] = sy;
      hU_s[b][uq * 4 + 2] = sz;
      hU_s[b][uq * 4 + 3] = sw;
    }
    __syncthreads();
    {  // score partial over this WG's 16-u slice, all T, own (b,t)
      const int gb = bg * GB + bS;
      const float* ap = attxT + ((size_t)gb * U_ + u0) * T_ + tS;
      float s = 0.f;
#pragma unroll
      for (int ui = 0; ui < 16; ++ui) {
        float e = tanh_fast(ap[(size_t)ui * T_] + hU_s[bS][ui]);
        s += e * Vs[ui];
      }
      sp_g[((size_t)(bg * WPG + w) * GB + bS) * T_ + tS] = s;
    }
    grp_barrier(ctr, WPG * (++epoch));  // B1: score partials visible

    // ========== P2: scores -> softmax -> z slice ==========================
    {
      const float* spp = sp_g + (size_t)bg * WPG * GB * T_ + bS * T_ + tS;
      float s = 0.f;
#pragma unroll 8
      for (int ww = 0; ww < WPG; ++ww) s += spp[(size_t)ww * GB * T_];
      sc_s[bS][tS] = s;
    }
    __syncthreads();
    if (tid < 256) {
      int b = tid >> 6, l = tid & 63;
      float m = fmaxf(sc_s[b][l], sc_s[b][l + 64]);
      for (int o = 32; o > 0; o >>= 1) m = fmaxf(m, __shfl_down(m, o));
      if (l == 0) m_s[b] = m;
    }
    __syncthreads();
    sc_s[bS][tS] = __expf(sc_s[bS][tS] - m_s[bS]);
    __syncthreads();
    if (tid < 256) {
      int b = tid >> 6, l = tid & 63;
      float s2 = sc_s[b][l] + sc_s[b][l + 64];
      for (int o = 32; o > 0; o >>= 1) s2 += __shfl_down(s2, o);
      if (l == 0) il_s[b] = 1.f / s2;
    }
    __syncthreads();
    {
      const int gb = bg * GB + bZ;
      float ax = 0.f, ay = 0.f, az = 0.f, aw = 0.f;
#pragma unroll
      for (int i = 0; i < 4; ++i) {
        int t2 = tkh * 4 + i;
        float4 xv = *(const float4*)(x + ((size_t)gb * T_ + t2) * D_ + u0 + d4 * 4);
        float a = sc_s[bZ][t2];
        ax += a * xv.x; ay += a * xv.y; az += a * xv.z; aw += a * xv.w;
      }
      red_s[(tkh * GB + bZ) * 4 + d4] = make_float4(ax, ay, az, aw);
    }
    __syncthreads();
    if (tid < 16) {
      int b = tid >> 2, dq = tid & 3;
      float sx = 0.f, sy = 0.f, sz = 0.f, sw = 0.f;
#pragma unroll
      for (int k = 0; k < 32; ++k) {
        float4 v4 = red_s[(k * GB + b) * 4 + dq];
        sx += v4.x; sy += v4.y; sz += v4.z; sw += v4.w;
      }
      float il = il_s[b];
      float4 o = make_float4(sx * il, sy * il, sz * il, sw * il);
      *(float4*)(z_g + (size_t)(bg * GB + b) * D_ + u0 + dq * 4) = o;
    }
    grp_barrier(ctr, WPG * (++epoch));  // B2: z visible

    // ========== P3: gza = z@Ak, gates, LSTM update, h exchange ============
    {
      int b = tid >> 7, idx = (tid & 127) * 4;
      *(float4*)&z_s[b][idx] =
          *(const float4*)(z_g + (size_t)(bg * GB + b) * D_ + idx);
    }
    __syncthreads();
    {
      float ax = 0.f, ay = 0.f, az = 0.f, aw = 0.f;
      const float* Ap = Ak + (size_t)(kh8 * 64) * G_ + gcol;
      const float* zp = &z_s[bA][kh8 * 64];
#pragma unroll 8
      for (int i = 0; i < 64; ++i) {
        float4 wv = *(const float4*)(Ap + (size_t)i * G_);
        float zv = zp[i];
        ax += zv * wv.x; ay += zv * wv.y; az += zv * wv.z; aw += zv * wv.w;
      }
      red_s[(kh8 * GB + bA) * 16 + c4] = make_float4(ax, ay, az, aw);
    }
    __syncthreads();
    if (tid < 256) {
      int b = tid >> 6, c = tid & 63;
      int cq = c >> 2, comp = c & 3;
      float gza = 0.f;
#pragma unroll
      for (int k = 0; k < 8; ++k)
        gza += ((const float*)&red_s[(k * GB + b) * 16 + cq])[comp];
      int g = c >> 4, ui = c & 15;
      int gb = bg * GB + b;
      float gate = xk[((size_t)gb * T_ + t) * G_ + g * U_ + u0 + ui] +
                   ghr_s[b][c] + gza;
      float gv = (g == 2) ? tanh_fast(gate)
                          : fminf(fmaxf(0.2f * gate + 0.5f, 0.f), 1.f);
      act_s[b][c] = gv;
    }
    __syncthreads();
    if (tid < 64) {
      int b = tid >> 4, ui = tid & 15;
      float i_ = act_s[b][ui];
      float f_ = act_s[b][16 + ui];
      float g_ = act_s[b][32 + ui];
      float o_ = act_s[b][48 + ui];
      float cn = f_ * c_s[b][ui] + i_ * g_;
      c_s[b][ui] = cn;
      float hn = o_ * tanh_fast(cn);
      int gb = bg * GB + b;
      h_g[(size_t)gb * U_ + u0 + ui] = hn;
      out[((size_t)gb * T_ + t) * U_ + u0 + ui] = hn;
    }
    grp_barrier(ctr, WPG * (++epoch));  // B3: h visible
    {
      int b = tid >> 7, idx = (tid & 127) * 4;
      *(float4*)&h_s[b][idx] =
          *(const float4*)(h_g + (size_t)(bg * GB + b) * U_ + idx);
    }
    __syncthreads();
  }
}

// ---------------------------------------------------------------------------
extern "C" void kernel_launch(void* const* d_in, const int* in_sizes, int n_in,
                              void* d_out, int out_size, void* d_ws,
                              size_t ws_size, hipStream_t stream) {
  (void)in_sizes;
  (void)n_in;
  (void)out_size;
  (void)ws_size;
  const float* x = (const float*)d_in[0];
  const float* Wk = (const float*)d_in[1];
  const float* Rk = (const float*)d_in[2];
  const float* Ak = (const float*)d_in[3];
  const float* Wa = (const float*)d_in[4];
  const float* Ua = (const float*)d_in[5];
  const float* Va = (const float*)d_in[6];
  const float* bias = (const float*)d_in[7];
  const float* ba = (const float*)d_in[8];
  float* out = (float*)d_out;

  char* ws = (char*)d_ws;
  float* xk = (float*)(ws);                     // 32 MiB
  float* attx = (float*)(ws + 33554432);        // 8 MiB
  float* attxT = (float*)(ws + 41943040);       // 8 MiB
  float* h_g = (float*)(ws + 50331648);         // 64 KiB
  float* sp_g = (float*)(ws + 50397184);        // 512 KiB
  float* z_g = (float*)(ws + 50921472);         // 64 KiB
  unsigned* bars = (unsigned*)(ws + 50987008);  // 2 KiB

  gemm_bias<<<dim3(G_ / 64, (B_ * T_) / 64), 256, 0, stream>>>(x, Wk, bias, xk, G_);
  gemm_bias<<<dim3(U_ / 64, (B_ * T_) / 64), 256, 0, stream>>>(x, Wa, ba, attx, U_);
  transpose_tu<<<dim3(64, B_), 256, 0, stream>>>(attx, attxT);
  hipMemsetAsync(bars, 0, NGRP * 64 * sizeof(unsigned), stream);

  attlstm_rec<<<dim3(NGRP * WPG), dim3(NT), 0, stream>>>(
      x, xk, attxT, Rk, Ak, Ua, Va, h_g, sp_g, z_g, bars, out);
}

// Round 3
// 3689.896 us; speedup vs baseline: 1.7126x; 1.7126x over previous
//
#include <hip/hip_runtime.h>
#include <math.h>

#define B_ 32
#define T_ 128
#define D_ 512
#define U_ 512
#define G_ 2048   // 4U
#define NGRP 8    // batch groups (one per XCD via blockIdx%8 swizzle)
#define GB 4      // batches per group
#define WPG 32    // workgroups per group
#define NT 512    // threads per WG
#define GK 512    // K dim of precompute GEMMs

__device__ __forceinline__ unsigned short f2bf(float v) {
  unsigned u = __float_as_uint(v);
  return (unsigned short)((u + 0x7FFFu + ((u >> 16) & 1u)) >> 16);
}
__device__ __forceinline__ float bf2f(unsigned short u) {
  return __uint_as_float(((unsigned)u) << 16);
}

// ---------------------------------------------------------------------------
// Precompute GEMM: C[M,N] = A[M,512] @ W[512,N] + bias  (bias may be null)
// MODE 0: fp32 row-major; MODE 1: bf16 row-major; MODE 2: fp32 (B,U,T)-transposed
// ---------------------------------------------------------------------------
template <int MODE>
__global__ __launch_bounds__(256) void gemm_bias_t(const float* __restrict__ A,
                                                   const float* __restrict__ W,
                                                   const float* __restrict__ bias,
                                                   void* __restrict__ Cout, int N) {
  __shared__ float As[16][68];
  __shared__ float Ws[16][64];
  const int tid = threadIdx.x;
  const int rowbase = blockIdx.y * 64;
  const int colbase = blockIdx.x * 64;
  const int ty = tid >> 4, tx = tid & 15;
  const int ar = tid >> 2, ak = (tid & 3) << 2;
  const int wk = tid >> 4, wc = (tid & 15) << 2;
  float acc[4][4] = {{0.f, 0.f, 0.f, 0.f}};
  for (int k0 = 0; k0 < GK; k0 += 16) {
    float4 av = *(const float4*)(A + (size_t)(rowbase + ar) * GK + k0 + ak);
    float4 wv = *(const float4*)(W + (size_t)(k0 + wk) * N + colbase + wc);
    __syncthreads();
    As[ak + 0][ar] = av.x;
    As[ak + 1][ar] = av.y;
    As[ak + 2][ar] = av.z;
    As[ak + 3][ar] = av.w;
    *(float4*)(&Ws[wk][wc]) = wv;
    __syncthreads();
#pragma unroll
    for (int kk = 0; kk < 16; ++kk) {
      float4 a = *(const float4*)(&As[kk][ty << 2]);
      float4 wv2 = *(const float4*)(&Ws[kk][tx << 2]);
      float a4[4] = {a.x, a.y, a.z, a.w};
      float w4[4] = {wv2.x, wv2.y, wv2.z, wv2.w};
#pragma unroll
      for (int i = 0; i < 4; ++i)
#pragma unroll
        for (int jj = 0; jj < 4; ++jj) acc[i][jj] += a4[i] * w4[jj];
    }
  }
  float4 bv = bias ? *(const float4*)(bias + colbase + (tx << 2))
                   : make_float4(0.f, 0.f, 0.f, 0.f);
#pragma unroll
  for (int i = 0; i < 4; ++i) {
    const int row = rowbase + (ty << 2) + i;
    float o[4] = {acc[i][0] + bv.x, acc[i][1] + bv.y, acc[i][2] + bv.z,
                  acc[i][3] + bv.w};
    if (MODE == 0) {
      *(float4*)((float*)Cout + (size_t)row * N + colbase + (tx << 2)) =
          make_float4(o[0], o[1], o[2], o[3]);
    } else if (MODE == 1) {
      ushort4 ob;
      ob.x = f2bf(o[0]); ob.y = f2bf(o[1]); ob.z = f2bf(o[2]); ob.w = f2bf(o[3]);
      *(ushort4*)((unsigned short*)Cout + (size_t)row * N + colbase + (tx << 2)) = ob;
    } else {
      const int b = row >> 7, tt = row & 127;
#pragma unroll
      for (int jj = 0; jj < 4; ++jj) {
        int u = colbase + (tx << 2) + jj;
        ((float*)Cout)[((size_t)b * U_ + u) * T_ + tt] = o[jj];
      }
    }
  }
}

__device__ __forceinline__ float tanh_fast(float x) {
  return 1.f - 2.f / (__expf(2.f * x) + 1.f);
}

// Per-group spin barrier (validated in R1/R2).
__device__ __forceinline__ void grp_barrier(unsigned* ctr, unsigned target) {
  __syncthreads();
  if (threadIdx.x == 0) {
    __hip_atomic_fetch_add(ctr, 1u, __ATOMIC_RELEASE, __HIP_MEMORY_SCOPE_AGENT);
    while (__hip_atomic_load(ctr, __ATOMIC_ACQUIRE, __HIP_MEMORY_SCOPE_AGENT) <
           target) {
      __builtin_amdgcn_s_sleep(2);
    }
  }
  __syncthreads();
}

// ---------------------------------------------------------------------------
// Weight-stationary recurrence. 8 groups x 32 WGs x 512 threads.
// WG w owns gate cols {g*512 + w*16 + ui} (Rk in regs), Um cols [w*16,+16)
// (regs), attxT slice in LDS. Context folded via xA: z@Ak = sum_t alpha_t *
// xA[t,col]  -> no z exchange, 2 barriers/step.
// ---------------------------------------------------------------------------
__global__ __launch_bounds__(NT) void attlstm_rec(
    const unsigned short* __restrict__ xk,  // (B,T,4U) bf16: x@kernel+bias
    const unsigned short* __restrict__ xA,  // (B,T,4U) bf16: x@attention_kernel
    const float* __restrict__ attxT,        // (B,U,T) fp32
    const float* __restrict__ Rk,           // (U,4U)
    const float* __restrict__ Um,           // (U,U)
    const float* __restrict__ V,            // (U)
    float* __restrict__ h_g,                // (B,U)
    float* __restrict__ sp_g,               // (NGRP,WPG,GB,T)
    unsigned* __restrict__ bars,            // (NGRP,64)
    float* __restrict__ out) {              // (B,T,U)
  const int bg = blockIdx.x & 7;
  const int w = blockIdx.x >> 3;
  const int tid = threadIdx.x;
  const int u0 = w * 16;
  const int tk = tid >> 4;  // 0..31 (K-chunk of 16)
  const int tc = tid & 15;  // col-quad id: gate=tc>>2, quad=(tc&3)
  const int gcol = (tc >> 2) * U_ + u0 + (tc & 3) * 4;
  const int wv = tid >> 6;
  const int lane = tid & 63;
  const int bS = tid >> 7;  // score/softmax role
  const int tS = tid & 127;
  // reducer role (tid<256)
  const int rb = tid >> 6;
  const int rc = tid & 63;
  const int rtc = rc >> 2, rcomp = rc & 3;
  const int rg = rtc >> 2;
  const int rui = ((rtc & 3) << 2) | rcomp;
  const int rcol = rg * U_ + u0 + rui;

  __shared__ float attx_l[16 * GB * T_];  // [uc][b][t] 32 KB
  __shared__ float h_s[GB][U_];           // 8 KB
  __shared__ float4 red2[8][GB][17];      // 8.7 KB
  __shared__ float hUred[8][GB][17];      // 2.2 KB
  __shared__ float sc_s[GB][T_];          // 2 KB
  __shared__ float hU_s[GB][16];
  __shared__ float act_s[GB][64];
  __shared__ float c_s[GB][16];
  __shared__ float m_s[GB], il_s[GB];
  __shared__ float Vs_l[16];

  // ---- stationary weights in registers ----
  float4 Rw[16];  // Rk[tk*16+i][gcol..+4]
  float Uw[16];   // Um[tk*16+i][u0+tc]
#pragma unroll
  for (int i = 0; i < 16; ++i)
    Rw[i] = *(const float4*)(Rk + (size_t)(tk * 16 + i) * G_ + gcol);
#pragma unroll
  for (int i = 0; i < 16; ++i)
    Uw[i] = Um[(size_t)(tk * 16 + i) * U_ + u0 + tc];

  // ---- preload attxT slice into LDS ----
  for (int idx = tid; idx < 16 * GB * T_; idx += NT) {
    int uc = idx >> 9;
    int b = (idx >> 7) & 3;
    int tt = idx & 127;
    attx_l[idx] = attxT[((size_t)(bg * GB + b) * U_ + u0 + uc) * T_ + tt];
  }
  for (int i = tid; i < GB * U_; i += NT) ((float*)h_s)[i] = 0.f;
  if (tid < GB * 16) ((float*)c_s)[tid] = 0.f;
  if (tid < 16) Vs_l[tid] = V[u0 + tid];
  unsigned* ctr = bars + bg * 64;
  unsigned epoch = 0;
  __syncthreads();

  for (int t = 0; t < T_; ++t) {
    // prefetch xk for reducer role (consumed in P2, after barrier)
    float xkv = 0.f;
    if (tid < 256)
      xkv = bf2f(xk[((size_t)(bg * GB + rb) * T_ + t) * G_ + rcol]);

    // ===== P1: gate partial (h@Rk) + hU partial (h@Um), register-stationary
    float4 accR[GB];
    float hUa[GB];
#pragma unroll
    for (int b = 0; b < GB; ++b) {
      float4 a = make_float4(0.f, 0.f, 0.f, 0.f);
      float hu = 0.f;
      const float* hp = &h_s[b][tk * 16];
#pragma unroll
      for (int i = 0; i < 16; ++i) {
        float hv = hp[i];
        a.x += hv * Rw[i].x;
        a.y += hv * Rw[i].y;
        a.z += hv * Rw[i].z;
        a.w += hv * Rw[i].w;
        hu += hv * Uw[i];
      }
      accR[b] = a;
      hUa[b] = hu;
    }
#pragma unroll
    for (int b = 0; b < GB; ++b) {
      float hu = hUa[b];
      hu += __shfl_down(hu, 32);
      hu += __shfl_down(hu, 16);
      if (lane < 16) hUred[wv][b][lane] = hu;
    }
    __syncthreads();
    if (tid < 64) {
      int b = tid >> 4, u = tid & 15;
      float s = 0.f;
#pragma unroll
      for (int k = 0; k < 8; ++k) s += hUred[k][b][u];
      hU_s[b][u] = s;
    }
    __syncthreads();
    {  // score partials over own 16-u slice, all T
      float s = 0.f;
      const float* ax = &attx_l[bS * T_ + tS];
#pragma unroll
      for (int uc = 0; uc < 16; ++uc) {
        float e = tanh_fast(ax[uc * (GB * T_)] + hU_s[bS][uc]);
        s += e * Vs_l[uc];
      }
      sp_g[((size_t)(bg * WPG + w) * GB + bS) * T_ + tS] = s;
    }
    grp_barrier(ctr, WPG * (++epoch));  // B1: score partials visible

    // ===== P2: softmax + context-folded gates + LSTM update
    {
      const float* spp = sp_g + (size_t)bg * WPG * GB * T_ + bS * T_ + tS;
      float s = 0.f;
#pragma unroll 8
      for (int ww = 0; ww < WPG; ++ww) s += spp[(size_t)ww * (GB * T_)];
      sc_s[bS][tS] = s;
    }
    __syncthreads();
    if (tid < 256) {
      int b = tid >> 6, l = tid & 63;
      float m = fmaxf(sc_s[b][l], sc_s[b][l + 64]);
      for (int o = 32; o > 0; o >>= 1) m = fmaxf(m, __shfl_down(m, o));
      if (l == 0) m_s[b] = m;
    }
    __syncthreads();
    sc_s[bS][tS] = __expf(sc_s[bS][tS] - m_s[bS]);
    __syncthreads();
    if (tid < 256) {
      int b = tid >> 6, l = tid & 63;
      float s2 = sc_s[b][l] + sc_s[b][l + 64];
      for (int o = 32; o > 0; o >>= 1) s2 += __shfl_down(s2, o);
      if (l == 0) il_s[b] = 1.f / s2;
    }
    __syncthreads();
    // gates_z = (sum_t e_t * xA[t,col]) * il ; combine with accR, reduce
#pragma unroll
    for (int b = 0; b < GB; ++b) {
      const unsigned short* xap =
          xA + ((size_t)(bg * GB + b) * T_ + tk * 4) * G_ + gcol;
      float4 az = make_float4(0.f, 0.f, 0.f, 0.f);
#pragma unroll
      for (int i = 0; i < 4; ++i) {
        ushort4 xv = *(const ushort4*)(xap + (size_t)i * G_);
        float al = sc_s[b][tk * 4 + i];
        az.x += al * bf2f(xv.x);
        az.y += al * bf2f(xv.y);
        az.z += al * bf2f(xv.z);
        az.w += al * bf2f(xv.w);
      }
      float il = il_s[b];
      float4 comb;
      comb.x = accR[b].x + il * az.x;
      comb.y = accR[b].y + il * az.y;
      comb.z = accR[b].z + il * az.z;
      comb.w = accR[b].w + il * az.w;
      comb.x += __shfl_down(comb.x, 32);
      comb.y += __shfl_down(comb.y, 32);
      comb.z += __shfl_down(comb.z, 32);
      comb.w += __shfl_down(comb.w, 32);
      comb.x += __shfl_down(comb.x, 16);
      comb.y += __shfl_down(comb.y, 16);
      comb.z += __shfl_down(comb.z, 16);
      comb.w += __shfl_down(comb.w, 16);
      if (lane < 16) red2[wv][b][lane] = comb;
    }
    __syncthreads();
    if (tid < 256) {
      float gsum = xkv;
      const float* r2 = (const float*)red2;
#pragma unroll
      for (int k = 0; k < 8; ++k)
        gsum += r2[(((size_t)(k * GB + rb) * 17) + rtc) * 4 + rcomp];
      float gv = (rg == 2) ? tanh_fast(gsum)
                           : fminf(fmaxf(0.2f * gsum + 0.5f, 0.f), 1.f);
      act_s[rb][rg * 16 + rui] = gv;
    }
    __syncthreads();
    if (tid < 64) {
      int b = tid >> 4, ui = tid & 15;
      float i_ = act_s[b][ui];
      float f_ = act_s[b][16 + ui];
      float g_ = act_s[b][32 + ui];
      float o_ = act_s[b][48 + ui];
      float cn = f_ * c_s[b][ui] + i_ * g_;
      c_s[b][ui] = cn;
      float hn = o_ * tanh_fast(cn);
      int gb = bg * GB + b;
      h_g[(size_t)gb * U_ + u0 + ui] = hn;
      out[((size_t)gb * T_ + t) * U_ + u0 + ui] = hn;
    }
    grp_barrier(ctr, WPG * (++epoch));  // B2: h visible
    {
      int b = tid >> 7, idx = (tid & 127) * 4;
      *(float4*)&h_s[b][idx] =
          *(const float4*)(h_g + (size_t)(bg * GB + b) * U_ + idx);
    }
    __syncthreads();
  }
}

// ---------------------------------------------------------------------------
extern "C" void kernel_launch(void* const* d_in, const int* in_sizes, int n_in,
                              void* d_out, int out_size, void* d_ws,
                              size_t ws_size, hipStream_t stream) {
  (void)in_sizes;
  (void)n_in;
  (void)out_size;
  (void)ws_size;
  const float* x = (const float*)d_in[0];
  const float* Wk = (const float*)d_in[1];
  const float* Rk = (const float*)d_in[2];
  const float* Ak = (const float*)d_in[3];
  const float* Wa = (const float*)d_in[4];
  const float* Ua = (const float*)d_in[5];
  const float* Va = (const float*)d_in[6];
  const float* bias = (const float*)d_in[7];
  const float* ba = (const float*)d_in[8];
  float* out = (float*)d_out;

  char* ws = (char*)d_ws;
  unsigned short* xk_b = (unsigned short*)(ws);            // 16 MiB
  unsigned short* xA_b = (unsigned short*)(ws + 16777216); // 16 MiB
  float* attxT = (float*)(ws + 33554432);                  // 8 MiB
  float* h_g = (float*)(ws + 41943040);                    // 64 KiB
  float* sp_g = (float*)(ws + 42008576);                   // 512 KiB
  unsigned* bars = (unsigned*)(ws + 42532864);             // 2 KiB

  gemm_bias_t<1><<<dim3(G_ / 64, (B_ * T_) / 64), 256, 0, stream>>>(
      x, Wk, bias, xk_b, G_);
  gemm_bias_t<1><<<dim3(G_ / 64, (B_ * T_) / 64), 256, 0, stream>>>(
      x, Ak, nullptr, xA_b, G_);
  gemm_bias_t<2><<<dim3(U_ / 64, (B_ * T_) / 64), 256, 0, stream>>>(
      x, Wa, ba, attxT, U_);
  hipMemsetAsync(bars, 0, NGRP * 64 * sizeof(unsigned), stream);

  attlstm_rec<<<dim3(NGRP * WPG), dim3(NT), 0, stream>>>(
      xk_b, xA_b, attxT, Rk, Ua, Va, h_g, sp_g, bars, out);
}

// Round 4
// 2450.900 us; speedup vs baseline: 2.5784x; 1.5055x over previous
//
#include <hip/hip_runtime.h>
#include <math.h>

#define B_ 32
#define T_ 128
#define D_ 512
#define U_ 512
#define G_ 2048   // 4U
#define NGRP 8    // batch groups
#define GB 4      // batches per group
#define WPG 32    // workgroups per group
#define NT 512    // threads per WG
#define GK 512    // K dim of precompute GEMMs

__device__ __forceinline__ unsigned short f2bf(float v) {
  unsigned u = __float_as_uint(v);
  return (unsigned short)((u + 0x7FFFu + ((u >> 16) & 1u)) >> 16);
}
__device__ __forceinline__ float bf2f(unsigned short u) {
  return __uint_as_float(((unsigned)u) << 16);
}

// Device-scope relaxed (cache-bypassing, fence-free) accessors.
__device__ __forceinline__ void dev_store(float* p, float v) {
  __hip_atomic_store(p, v, __ATOMIC_RELAXED, __HIP_MEMORY_SCOPE_AGENT);
}
__device__ __forceinline__ float dev_load(const float* p) {
  return __hip_atomic_load(p, __ATOMIC_RELAXED, __HIP_MEMORY_SCOPE_AGENT);
}

// ---------------------------------------------------------------------------
// Precompute GEMM: C[M,N] = A[M,512] @ W[512,N] + bias  (bias may be null)
// MODE 1: bf16 row-major; MODE 2: fp32 (B,U,T)-transposed
// ---------------------------------------------------------------------------
template <int MODE>
__global__ __launch_bounds__(256) void gemm_bias_t(const float* __restrict__ A,
                                                   const float* __restrict__ W,
                                                   const float* __restrict__ bias,
                                                   void* __restrict__ Cout, int N) {
  __shared__ float As[16][68];
  __shared__ float Ws[16][64];
  const int tid = threadIdx.x;
  const int rowbase = blockIdx.y * 64;
  const int colbase = blockIdx.x * 64;
  const int ty = tid >> 4, tx = tid & 15;
  const int ar = tid >> 2, ak = (tid & 3) << 2;
  const int wk = tid >> 4, wc = (tid & 15) << 2;
  float acc[4][4] = {{0.f, 0.f, 0.f, 0.f}};
  for (int k0 = 0; k0 < GK; k0 += 16) {
    float4 av = *(const float4*)(A + (size_t)(rowbase + ar) * GK + k0 + ak);
    float4 wv = *(const float4*)(W + (size_t)(k0 + wk) * N + colbase + wc);
    __syncthreads();
    As[ak + 0][ar] = av.x;
    As[ak + 1][ar] = av.y;
    As[ak + 2][ar] = av.z;
    As[ak + 3][ar] = av.w;
    *(float4*)(&Ws[wk][wc]) = wv;
    __syncthreads();
#pragma unroll
    for (int kk = 0; kk < 16; ++kk) {
      float4 a = *(const float4*)(&As[kk][ty << 2]);
      float4 wv2 = *(const float4*)(&Ws[kk][tx << 2]);
      float a4[4] = {a.x, a.y, a.z, a.w};
      float w4[4] = {wv2.x, wv2.y, wv2.z, wv2.w};
#pragma unroll
      for (int i = 0; i < 4; ++i)
#pragma unroll
        for (int jj = 0; jj < 4; ++jj) acc[i][jj] += a4[i] * w4[jj];
    }
  }
  float4 bv = bias ? *(const float4*)(bias + colbase + (tx << 2))
                   : make_float4(0.f, 0.f, 0.f, 0.f);
#pragma unroll
  for (int i = 0; i < 4; ++i) {
    const int row = rowbase + (ty << 2) + i;
    float o[4] = {acc[i][0] + bv.x, acc[i][1] + bv.y, acc[i][2] + bv.z,
                  acc[i][3] + bv.w};
    if (MODE == 1) {
      ushort4 ob;
      ob.x = f2bf(o[0]); ob.y = f2bf(o[1]); ob.z = f2bf(o[2]); ob.w = f2bf(o[3]);
      *(ushort4*)((unsigned short*)Cout + (size_t)row * N + colbase + (tx << 2)) = ob;
    } else {
      const int b = row >> 7, tt = row & 127;
#pragma unroll
      for (int jj = 0; jj < 4; ++jj) {
        int u = colbase + (tx << 2) + jj;
        ((float*)Cout)[((size_t)b * U_ + u) * T_ + tt] = o[jj];
      }
    }
  }
}

__device__ __forceinline__ float tanh_fast(float x) {
  return 1.f - 2.f / (__expf(2.f * x) + 1.f);
}

// ---------------------------------------------------------------------------
// Fence-free group barrier. All cross-WG data goes through device-scope
// relaxed (MALL-coherent, cache-bypassing) loads/stores, so no acquire/
// release cache maintenance is needed. __syncthreads drains vmcnt(0)
// (documented compiler behavior) => this WG's dev_stores have completed at
// the coherence point before the counter bump.
// ---------------------------------------------------------------------------
__device__ __forceinline__ void grp_barrier(unsigned* ctr, unsigned target) {
  __syncthreads();
  if (threadIdx.x == 0) {
    __hip_atomic_fetch_add(ctr, 1u, __ATOMIC_RELAXED, __HIP_MEMORY_SCOPE_AGENT);
    while (__hip_atomic_load(ctr, __ATOMIC_RELAXED, __HIP_MEMORY_SCOPE_AGENT) <
           target) {
      __builtin_amdgcn_s_sleep(1);
    }
  }
  __syncthreads();
}

// ---------------------------------------------------------------------------
// Weight-stationary recurrence. 8 groups x 32 WGs x 512 threads.
// WG w owns gate cols {g*512 + w*16 + ui} (Rk in regs), Um cols [w*16,+16)
// (regs), attxT slice in LDS. z@Ak folded via xA. 2 barriers/step.
// ---------------------------------------------------------------------------
__global__ __launch_bounds__(NT) void attlstm_rec(
    const unsigned short* __restrict__ xk,  // (B,T,4U) bf16
    const unsigned short* __restrict__ xA,  // (B,T,4U) bf16
    const float* __restrict__ attxT,        // (B,U,T) fp32
    const float* __restrict__ Rk,           // (U,4U)
    const float* __restrict__ Um,           // (U,U)
    const float* __restrict__ V,            // (U)
    float* __restrict__ h_g,                // (B,U)
    float* __restrict__ sp_g,               // (NGRP,WPG,GB,T)
    unsigned* __restrict__ bars,            // (NGRP,64)
    float* __restrict__ out) {              // (B,T,U)
  const int bg = blockIdx.x & 7;
  const int w = blockIdx.x >> 3;
  const int tid = threadIdx.x;
  const int u0 = w * 16;
  const int tk = tid >> 4;  // 0..31 (K-chunk of 16)
  const int tc = tid & 15;  // col-quad id
  const int gcol = (tc >> 2) * U_ + u0 + (tc & 3) * 4;
  const int wv = tid >> 6;
  const int lane = tid & 63;
  const int bS = tid >> 7;
  const int tS = tid & 127;
  const int rb = tid >> 6;  // reducer role (tid<256)
  const int rc = tid & 63;
  const int rtc = rc >> 2, rcomp = rc & 3;
  const int rg = rtc >> 2;
  const int rui = ((rtc & 3) << 2) | rcomp;
  const int rcol = rg * U_ + u0 + rui;

  __shared__ float attx_l[16 * GB * T_];  // 32 KB
  __shared__ float h_s[GB][U_];           // 8 KB
  __shared__ float4 red2[8][GB][17];
  __shared__ float hUred[8][GB][17];
  __shared__ float sc_s[GB][T_];
  __shared__ float hU_s[GB][16];
  __shared__ float act_s[GB][64];
  __shared__ float c_s[GB][16];
  __shared__ float m_s[GB], il_s[GB];
  __shared__ float Vs_l[16];

  float4 Rw[16];
  float Uw[16];
#pragma unroll
  for (int i = 0; i < 16; ++i)
    Rw[i] = *(const float4*)(Rk + (size_t)(tk * 16 + i) * G_ + gcol);
#pragma unroll
  for (int i = 0; i < 16; ++i)
    Uw[i] = Um[(size_t)(tk * 16 + i) * U_ + u0 + tc];

  for (int idx = tid; idx < 16 * GB * T_; idx += NT) {
    int uc = idx >> 9;
    int b = (idx >> 7) & 3;
    int tt = idx & 127;
    attx_l[idx] = attxT[((size_t)(bg * GB + b) * U_ + u0 + uc) * T_ + tt];
  }
  for (int i = tid; i < GB * U_; i += NT) ((float*)h_s)[i] = 0.f;
  if (tid < GB * 16) ((float*)c_s)[tid] = 0.f;
  if (tid < 16) Vs_l[tid] = V[u0 + tid];
  unsigned* ctr = bars + bg * 64;
  unsigned epoch = 0;
  __syncthreads();

  for (int t = 0; t < T_; ++t) {
    float xkv = 0.f;
    if (tid < 256)
      xkv = bf2f(xk[((size_t)(bg * GB + rb) * T_ + t) * G_ + rcol]);

    // ===== P1: h@Rk partial + h@Um partial (register-stationary)
    float4 accR[GB];
    float hUa[GB];
#pragma unroll
    for (int b = 0; b < GB; ++b) {
      float4 a = make_float4(0.f, 0.f, 0.f, 0.f);
      float hu = 0.f;
      const float* hp = &h_s[b][tk * 16];
#pragma unroll
      for (int i = 0; i < 16; ++i) {
        float hv = hp[i];
        a.x += hv * Rw[i].x;
        a.y += hv * Rw[i].y;
        a.z += hv * Rw[i].z;
        a.w += hv * Rw[i].w;
        hu += hv * Uw[i];
      }
      accR[b] = a;
      hUa[b] = hu;
    }
#pragma unroll
    for (int b = 0; b < GB; ++b) {
      float hu = hUa[b];
      hu += __shfl_down(hu, 32);
      hu += __shfl_down(hu, 16);
      if (lane < 16) hUred[wv][b][lane] = hu;
    }
    __syncthreads();
    if (tid < 64) {
      int b = tid >> 4, u = tid & 15;
      float s = 0.f;
#pragma unroll
      for (int k = 0; k < 8; ++k) s += hUred[k][b][u];
      hU_s[b][u] = s;
    }
    __syncthreads();
    {  // score partials over own 16-u slice, all T
      float s = 0.f;
      const float* ax = &attx_l[bS * T_ + tS];
#pragma unroll
      for (int uc = 0; uc < 16; ++uc) {
        float e = tanh_fast(ax[uc * (GB * T_)] + hU_s[bS][uc]);
        s += e * Vs_l[uc];
      }
      dev_store(&sp_g[((size_t)(bg * WPG + w) * GB + bS) * T_ + tS], s);
    }
    grp_barrier(ctr, WPG * (++epoch));  // B1

    // ===== P2: softmax + context-folded gates + LSTM update
    {
      const float* spp = sp_g + (size_t)bg * WPG * GB * T_ + bS * T_ + tS;
      float s = 0.f;
#pragma unroll 8
      for (int ww = 0; ww < WPG; ++ww) s += dev_load(spp + (size_t)ww * (GB * T_));
      sc_s[bS][tS] = s;
    }
    __syncthreads();
    if (tid < 256) {
      int b = tid >> 6, l = tid & 63;
      float m = fmaxf(sc_s[b][l], sc_s[b][l + 64]);
      for (int o = 32; o > 0; o >>= 1) m = fmaxf(m, __shfl_down(m, o));
      if (l == 0) m_s[b] = m;
    }
    __syncthreads();
    sc_s[bS][tS] = __expf(sc_s[bS][tS] - m_s[bS]);
    __syncthreads();
    if (tid < 256) {
      int b = tid >> 6, l = tid & 63;
      float s2 = sc_s[b][l] + sc_s[b][l + 64];
      for (int o = 32; o > 0; o >>= 1) s2 += __shfl_down(s2, o);
      if (l == 0) il_s[b] = 1.f / s2;
    }
    __syncthreads();
#pragma unroll
    for (int b = 0; b < GB; ++b) {
      const unsigned short* xap =
          xA + ((size_t)(bg * GB + b) * T_ + tk * 4) * G_ + gcol;
      float4 az = make_float4(0.f, 0.f, 0.f, 0.f);
#pragma unroll
      for (int i = 0; i < 4; ++i) {
        ushort4 xv = *(const ushort4*)(xap + (size_t)i * G_);
        float al = sc_s[b][tk * 4 + i];
        az.x += al * bf2f(xv.x);
        az.y += al * bf2f(xv.y);
        az.z += al * bf2f(xv.z);
        az.w += al * bf2f(xv.w);
      }
      float il = il_s[b];
      float4 comb;
      comb.x = accR[b].x + il * az.x;
      comb.y = accR[b].y + il * az.y;
      comb.z = accR[b].z + il * az.z;
      comb.w = accR[b].w + il * az.w;
      comb.x += __shfl_down(comb.x, 32);
      comb.y += __shfl_down(comb.y, 32);
      comb.z += __shfl_down(comb.z, 32);
      comb.w += __shfl_down(comb.w, 32);
      comb.x += __shfl_down(comb.x, 16);
      comb.y += __shfl_down(comb.y, 16);
      comb.z += __shfl_down(comb.z, 16);
      comb.w += __shfl_down(comb.w, 16);
      if (lane < 16) red2[wv][b][lane] = comb;
    }
    __syncthreads();
    if (tid < 256) {
      float gsum = xkv;
      const float* r2 = (const float*)red2;
#pragma unroll
      for (int k = 0; k < 8; ++k)
        gsum += r2[(((size_t)(k * GB + rb) * 17) + rtc) * 4 + rcomp];
      float gv = (rg == 2) ? tanh_fast(gsum)
                           : fminf(fmaxf(0.2f * gsum + 0.5f, 0.f), 1.f);
      act_s[rb][rg * 16 + rui] = gv;
    }
    __syncthreads();
    if (tid < 64) {
      int b = tid >> 4, ui = tid & 15;
      float i_ = act_s[b][ui];
      float f_ = act_s[b][16 + ui];
      float g_ = act_s[b][32 + ui];
      float o_ = act_s[b][48 + ui];
      float cn = f_ * c_s[b][ui] + i_ * g_;
      c_s[b][ui] = cn;
      float hn = o_ * tanh_fast(cn);
      int gb = bg * GB + b;
      dev_store(&h_g[(size_t)gb * U_ + u0 + ui], hn);
      out[((size_t)gb * T_ + t) * U_ + u0 + ui] = hn;
    }
    grp_barrier(ctr, WPG * (++epoch));  // B2
    {
      const float* hg = h_g + (size_t)(bg * GB) * U_;
      int base = tid * 4;
      float4 hv;
      hv.x = dev_load(hg + base + 0);
      hv.y = dev_load(hg + base + 1);
      hv.z = dev_load(hg + base + 2);
      hv.w = dev_load(hg + base + 3);
      *(float4*)&((float*)h_s)[base] = hv;
    }
    __syncthreads();
  }
}

// ---------------------------------------------------------------------------
extern "C" void kernel_launch(void* const* d_in, const int* in_sizes, int n_in,
                              void* d_out, int out_size, void* d_ws,
                              size_t ws_size, hipStream_t stream) {
  (void)in_sizes;
  (void)n_in;
  (void)out_size;
  (void)ws_size;
  const float* x = (const float*)d_in[0];
  const float* Wk = (const float*)d_in[1];
  const float* Rk = (const float*)d_in[2];
  const float* Ak = (const float*)d_in[3];
  const float* Wa = (const float*)d_in[4];
  const float* Ua = (const float*)d_in[5];
  const float* Va = (const float*)d_in[6];
  const float* bias = (const float*)d_in[7];
  const float* ba = (const float*)d_in[8];
  float* out = (float*)d_out;

  char* ws = (char*)d_ws;
  unsigned short* xk_b = (unsigned short*)(ws);            // 16 MiB
  unsigned short* xA_b = (unsigned short*)(ws + 16777216); // 16 MiB
  float* attxT = (float*)(ws + 33554432);                  // 8 MiB
  float* h_g = (float*)(ws + 41943040);                    // 64 KiB
  float* sp_g = (float*)(ws + 42008576);                   // 512 KiB
  unsigned* bars = (unsigned*)(ws + 42532864);             // 2 KiB

  gemm_bias_t<1><<<dim3(G_ / 64, (B_ * T_) / 64), 256, 0, stream>>>(
      x, Wk, bias, xk_b, G_);
  gemm_bias_t<1><<<dim3(G_ / 64, (B_ * T_) / 64), 256, 0, stream>>>(
      x, Ak, nullptr, xA_b, G_);
  gemm_bias_t<2><<<dim3(U_ / 64, (B_ * T_) / 64), 256, 0, stream>>>(
      x, Wa, ba, attxT, U_);
  hipMemsetAsync(bars, 0, NGRP * 64 * sizeof(unsigned), stream);

  attlstm_rec<<<dim3(NGRP * WPG), dim3(NT), 0, stream>>>(
      xk_b, xA_b, attxT, Rk, Ua, Va, h_g, sp_g, bars, out);
}